// Round 15
// baseline (119.422 us; speedup 1.0000x reference)
//
#include <hip/hip_runtime.h>
#include <math.h>

#define N 64
#define F 64
#define W 40
#define D 512
#define LSM 9.0f
#define LLSE 6.0f
#define MARG 0.2f
#define ESTR 56  // Es row stride in halves

typedef _Float16 f16x8 __attribute__((ext_vector_type(8)));
typedef _Float16 f16x4 __attribute__((ext_vector_type(4)));
typedef float f32x4 __attribute__((ext_vector_type(4)));

__device__ inline void gll16(const void* g, void* l) {
  __builtin_amdgcn_global_load_lds(
      (const __attribute__((address_space(1))) unsigned int*)g,
      (__attribute__((address_space(3))) unsigned int*)l, 16, 0, 0);
}

// layouts (halves), K-chunked (8 chunks of 64) + XOR swizzle baked in:
//  img_h per i: [ch8][f64][64],  halfidx ^ ((f&7)<<3)               (32768)
//  cap_h per j: [ch8][w48][64], halfidx ^ ((w&7)<<3), rows 40..47=0 (24576)
//  G_h  per j: [w48][64] linear, zero outside 40 rows/48 cols       (3072)

// ---------------- k_pre: grid 320 x 512 (unchanged, proven) ----------------
__global__ __launch_bounds__(512) void k_pre(
    const float* __restrict__ img, const float* __restrict__ cap,
    _Float16* __restrict__ img_h, _Float16* __restrict__ cap_h,
    _Float16* __restrict__ G_h, float* __restrict__ n1) {
  __shared__ __align__(16) _Float16 capT[4 * 48 * 128];  // 48 KB (cap blocks only)
  int t = threadIdx.x;
  int b = blockIdx.x;
  if (b < 256) {
    int i = b >> 2;
    int f = ((b & 3) << 4) + (t >> 5);
    int q = t & 31;  // 16 halves per thread
    const float* row = img + ((size_t)i * F + f) * D + q * 16;
    _Float16* dsti = img_h + (size_t)i * 32768;
    int fsw = (f & 7) << 3;
    float s = 0.f;
    int d0 = q * 16;
    int ch = d0 >> 6, din = d0 & 63;
#pragma unroll
    for (int k = 0; k < 2; ++k) {
      float4 u = *(const float4*)(row + k * 8);
      float4 v = *(const float4*)(row + k * 8 + 4);
      s += u.x * u.x + u.y * u.y + u.z * u.z + u.w * u.w;
      s += v.x * v.x + v.y * v.y + v.z * v.z + v.w * v.w;
      f16x8 h;
      h[0] = (_Float16)u.x; h[1] = (_Float16)u.y; h[2] = (_Float16)u.z; h[3] = (_Float16)u.w;
      h[4] = (_Float16)v.x; h[5] = (_Float16)v.y; h[6] = (_Float16)v.z; h[7] = (_Float16)v.w;
      *(f16x8*)(dsti + ch * 4096 + f * 64 + ((din + k * 8) ^ fsw)) = h;
    }
    s += __shfl_xor(s, 1);
    s += __shfl_xor(s, 2);
    s += __shfl_xor(s, 4);
    s += __shfl_xor(s, 8);
    s += __shfl_xor(s, 16);
    if (q == 0) n1[i * F + f] = sqrtf(s);
  } else {
    int j = b - 256;
    int lane = t & 63, wv = t >> 6;
    const float* src = cap + (size_t)j * W * D;
    _Float16* dst = cap_h + (size_t)j * 24576;
#pragma unroll
    for (int k = 0; k < 6; ++k) {
      int slot = t + k * 512;  // 48 rows x 64 col-chunks
      int w = slot >> 6, d = (slot & 63) * 8;
      float4 u = {0.f, 0.f, 0.f, 0.f}, v = {0.f, 0.f, 0.f, 0.f};
      if (w < W) {
        u = *(const float4*)(src + (size_t)w * D + d);
        v = *(const float4*)(src + (size_t)w * D + d + 4);
      }
      f16x8 h;
      h[0] = (_Float16)u.x; h[1] = (_Float16)u.y; h[2] = (_Float16)u.z; h[3] = (_Float16)u.w;
      h[4] = (_Float16)v.x; h[5] = (_Float16)v.y; h[6] = (_Float16)v.z; h[7] = (_Float16)v.w;
      int wsw = (w & 7) << 3;
      int ch2 = d >> 6, din2 = d & 63;
      *(f16x8*)(dst + ch2 * 3072 + w * 64 + (din2 ^ wsw)) = h;
      int chO = d >> 7, dinO = d & 127;
      *(f16x8*)(capT + chO * 6144 + w * 128 + (dinO ^ wsw)) = h;
    }
    __syncthreads();
    int lane2 = t & 63;
    int rlo = lane2 & 15, hi = lane2 >> 4;
    int koff = hi * 8, sw = (rlo & 7) << 3;
    _Float16* gb = G_h + (size_t)j * 3072;
    for (int tile = wv; tile < 9; tile += 8) {
      int mt = tile / 3, kt = tile % 3;
      f32x4 acc = (f32x4)0.f;
#pragma unroll
      for (int ks = 0; ks < 16; ++ks) {
        int kk = ks * 32 + koff;
        int ch = kk >> 7, din = (kk & 127) ^ sw;
        f16x8 af = *(const f16x8*)(capT + ch * 6144 + (mt * 16 + rlo) * 128 + din);
        f16x8 bf = *(const f16x8*)(capT + ch * 6144 + (kt * 16 + rlo) * 128 + din);
        acc = __builtin_amdgcn_mfma_f32_16x16x32_f16(af, bf, acc, 0, 0, 0);
      }
#pragma unroll
      for (int r = 0; r < 4; ++r) {
        int w = mt * 16 + hi * 4 + r, k = kt * 16 + rlo;
        float val = (w < W && k < W) ? acc[r] : 0.f;
        gb[w * 64 + k] = (_Float16)val;
      }
    }
    // zero G cols 48..63 (K-tail of P2 reads E pad -> A=G cols must be 0)
    if (t < 96) {
      int w = t >> 1, c8 = 48 + (t & 1) * 8;
      *(f16x8*)(gb + w * 64 + c8) = (f16x8)(_Float16)0.f;
    }
  }
}

// ---------------- k_fused: 256 blocks x 512 thr = 2 blocks/CU ----------------
// GEMM: 192x256 C-tile (4 caps x 4 imgs), BK=64, SINGLE-buffered 56KB staging
// -> LDS 57.6KB -> 2 blocks/CU: the co-resident block's compute fills this
// block's vmcnt drains and epilogue chains (cross-block TLP, m114).
// Wave (wm,wn of 2x4): 96x64 output = TWO complete (j,i) pairs in registers.
__global__ __launch_bounds__(512, 4) void k_fused(
    const _Float16* __restrict__ img_h, const _Float16* __restrict__ cap_h,
    const int* __restrict__ imgL, const int* __restrict__ capL,
    const float* __restrict__ n1g, const _Float16* __restrict__ G_h,
    float* __restrict__ S) {
  __shared__ __align__(16) char buf[57600];  // 56KB staging; Es slices alias + 256B pad

  int t = threadIdx.x;
  int lane = t & 63, wv = t >> 6;
  int rlo = lane & 15, hi = lane >> 4;
  int koff = hi * 8;
  int sw = (rlo & 7) << 3;
  int wm = wv >> 2, wn = wv & 3;  // 2 x 4 wave grid

  int bid = blockIdx.x;
  int xcd = bid & 7, s0 = bid >> 3;
  int bj = (xcd & 3) * 4 + (s0 & 3);   // M-tile in [0,16)
  int bi = (xcd >> 2) * 8 + (s0 >> 2); // N-tile in [0,16)

  int i = bi * 4 + wn;       // this wave's image
  int ja = bj * 4 + wm * 2;  // pair a caption; pair b = ja+1
  int iL = imgL[i];          // oldest vmcnt entries; first vmcnt(0) covers them
  int cLa = capL[ja], cLb = capL[ja + 1];

  const char* capb = (const char*)cap_h + (size_t)bj * 4 * 49152;
  const char* imgb = (const char*)img_h + (size_t)bi * 4 * 65536;

  // 7 staging descriptors/wave: 56 x 1KB segs per K-tile (A 24KB | B 32KB)
  const char* bsrc[7];
  int cstr[7], mdst[7];
#pragma unroll
  for (int s = 0; s < 7; ++s) {
    int m = s * 8 + wv;
    if (m < 24) {
      bsrc[s] = capb + (m / 6) * 49152 + (m % 6) * 1024 + lane * 16;
      cstr[s] = 6144;
    } else {
      int e = m - 24;
      bsrc[s] = imgb + (e >> 3) * 65536 + (e & 7) * 1024 + lane * 16;
      cstr[s] = 8192;
    }
    mdst[s] = m * 1024;
  }

  f32x4 acc[6][4];
#pragma unroll
  for (int mt = 0; mt < 6; ++mt)
#pragma unroll
    for (int nt = 0; nt < 4; ++nt) acc[mt][nt] = (f32x4)0.f;

  // ---- K-loop: single-buffer, drain per tile; other block fills the drain ----
#pragma unroll
  for (int c = 0; c < 8; ++c) {
#pragma unroll
    for (int s = 0; s < 7; ++s) gll16(bsrc[s] + c * cstr[s], buf + mdst[s]);
    asm volatile("s_waitcnt vmcnt(0)" ::: "memory");
    __builtin_amdgcn_s_barrier();  // all waves' tile-c data landed
    __builtin_amdgcn_sched_barrier(0);
    const _Float16* Al = (const _Float16*)buf;                        // 4 x [48][64]
    const _Float16* Bl = (const _Float16*)(buf + 24576) + wn * 4096;  // my i: [64][64]
#pragma unroll
    for (int ks = 0; ks < 2; ++ks) {
      int col = (ks * 32 + koff) ^ sw;
      f16x8 bf[4], af[6];
#pragma unroll
      for (int nt = 0; nt < 4; ++nt) bf[nt] = *(const f16x8*)(Bl + (nt * 16 + rlo) * 64 + col);
#pragma unroll
      for (int mt = 0; mt < 6; ++mt) {
        int blk = wm * 2 + (mt >= 3 ? 1 : 0);
        int w = (mt >= 3 ? mt - 3 : mt) * 16 + rlo;
        af[mt] = *(const f16x8*)(Al + blk * 3072 + w * 64 + col);
      }
      __builtin_amdgcn_s_setprio(1);
#pragma unroll
      for (int mt = 0; mt < 6; ++mt)
#pragma unroll
        for (int nt = 0; nt < 4; ++nt)
          acc[mt][nt] = __builtin_amdgcn_mfma_f32_16x16x32_f16(af[mt], bf[nt], acc[mt][nt], 0, 0, 0);
      __builtin_amdgcn_s_setprio(0);
    }
    __builtin_amdgcn_sched_barrier(0);
    __builtin_amdgcn_s_barrier();  // all reads done -> next tile may overwrite
  }

  // ---- epilogue v2: wave-private, zero barriers, per pair ----
  _Float16* Ew = (_Float16*)(buf + wv * 7168);  // [64][ESTR=56] halves
  // zero this wave's Es slice (stale staging data; K-tail cols must be finite)
#pragma unroll
  for (int z = 0; z < 7; ++z)
    *(f16x8*)(buf + wv * 7168 + (z * 64 + lane) * 16) = (f16x8)(_Float16)0.f;
  if (wv == 7 && lane < 16)  // wave-7 row-63 K-tail overread target (pad region)
    *(f16x8*)(buf + 57344 + lane * 16) = (f16x8)(_Float16)0.f;

  float n1lane = n1g[i * F + lane];

#pragma unroll
  for (int p = 0; p < 2; ++p) {
    int j = ja + p;
    int cL = p ? cLb : cLa;
    int mb = p * 3;

    // rnorm: rinv per w from sum_f leaky(A)^2 (f-masked)
    float rinv[3][4];
#pragma unroll
    for (int mt = 0; mt < 3; ++mt)
#pragma unroll
      for (int r = 0; r < 4; ++r) {
        float s = 0.f;
#pragma unroll
        for (int nt = 0; nt < 4; ++nt) {
          float a = acc[mb + mt][nt][r];
          float l = a > 0.f ? a : 0.1f * a;
          s += ((nt * 16 + rlo) < iL) ? l * l : 0.f;
        }
#pragma unroll
        for (int d = 1; d < 16; d <<= 1) s += __shfl_xor(s, d);
        rinv[mt][r] = 1.f / (sqrtf(s) + 1e-8f);
      }

    // fused softmax (logits in [-9,9] -> no max pass) + sn + E to regs + Es write
    float sn[4] = {0.f, 0.f, 0.f, 0.f};
    f16x4 evs[3][4];  // lane-owned E[f = nt*16+rlo][w = mt*16+hi*4+r]
#pragma unroll
    for (int mt = 0; mt < 3; ++mt)
#pragma unroll
      for (int nt = 0; nt < 4; ++nt) {
        f16x4 ev;
#pragma unroll
        for (int r = 0; r < 4; ++r) {
          int w = mt * 16 + hi * 4 + r;
          float a = acc[mb + mt][nt][r];
          float l = a > 0.f ? a : 0.1f * a;
          float e = (w < cL) ? __expf(LSM * l * rinv[mt][r]) : 0.f;
          sn[nt] = fmaf(e, a, sn[nt]);
          ev[r] = (_Float16)e;
        }
        evs[mt][nt] = ev;
        *(f16x4*)(Ew + (nt * 16 + rlo) * ESTR + mt * 16 + hi * 4) = ev;
      }
#pragma unroll
    for (int nt = 0; nt < 4; ++nt) {
      sn[nt] += __shfl_xor(sn[nt], 16);
      sn[nt] += __shfl_xor(sn[nt], 32);
    }

    // P2 = G x E^T (24 MFMA): C[w][f] -> f on lanes (col = rlo)
    const _Float16* gB = G_h + (size_t)j * 3072;
    f32x4 P2[3][4];
#pragma unroll
    for (int wb = 0; wb < 3; ++wb)
#pragma unroll
      for (int fb = 0; fb < 4; ++fb) P2[wb][fb] = (f32x4)0.f;
#pragma unroll
    for (int ks2 = 0; ks2 < 2; ++ks2) {
      int kk2 = ks2 * 32 + koff;
      f16x8 ga[3], eb[4];
#pragma unroll
      for (int wb = 0; wb < 3; ++wb)
        ga[wb] = *(const f16x8*)(gB + (wb * 16 + rlo) * 64 + kk2);
#pragma unroll
      for (int fb = 0; fb < 4; ++fb)
        eb[fb] = *(const f16x8*)(Ew + (fb * 16 + rlo) * ESTR + kk2);
#pragma unroll
      for (int wb = 0; wb < 3; ++wb)
#pragma unroll
        for (int fb = 0; fb < 4; ++fb)
          P2[wb][fb] = __builtin_amdgcn_mfma_f32_16x16x32_f16(ga[wb], eb[fb], P2[wb][fb], 0, 0, 0);
    }

    // tail: n2^2[f] from registers; sim+exp once per (lane, fb); LSE reduce
    float ef = 0.f;
#pragma unroll
    for (int fb = 0; fb < 4; ++fb) {
      int f = fb * 16 + rlo;
      float n2s = 0.f;
#pragma unroll
      for (int wb = 0; wb < 3; ++wb)
#pragma unroll
        for (int r = 0; r < 4; ++r)
          n2s = fmaf(P2[wb][fb][r], (float)evs[wb][fb][r], n2s);
      n2s += __shfl_xor(n2s, 16);
      n2s += __shfl_xor(n2s, 32);
      float nm = sn[fb];
      float n1v = __shfl(n1lane, f);
      float denom = n1v * sqrtf(fmaxf(n2s, 0.f));
      float sim = nm / fmaxf(denom, 1e-20f);
      ef += (f < iL) ? __expf(LLSE * sim) : 0.f;
    }
    ef += __shfl_xor(ef, 1);
    ef += __shfl_xor(ef, 2);
    ef += __shfl_xor(ef, 4);
    ef += __shfl_xor(ef, 8);
    if (lane == 0) S[(j << 6) + i] = __logf(ef) * (1.f / LLSE);
  }
}

// ---------------- k_loss ----------------
__global__ void k_loss(const float* __restrict__ S, float* __restrict__ out) {
  __shared__ float red[128];
  int t = threadIdx.x;
  float m = -1e30f;
  if (t < 64) {
    int a = t;
    float da = S[a * N + a];
    for (int b = 0; b < N; ++b)
      if (b != a) m = fmaxf(m, MARG + S[a * N + b] - da);
  } else {
    int b = t - 64;
    float db = S[b * N + b];
    for (int a = 0; a < N; ++a)
      if (a != b) m = fmaxf(m, MARG + S[a * N + b] - db);
  }
  red[t] = fmaxf(m, 0.f);
  __syncthreads();
  if (t < 64) {
    float v = red[t] + red[t + 64];
#pragma unroll
    for (int off = 1; off < 64; off <<= 1) v += __shfl_xor(v, off);
    if (t == 0) *out = v;
  }
}

extern "C" void kernel_launch(void* const* d_in, const int* in_sizes, int n_in,
                              void* d_out, int out_size, void* d_ws, size_t ws_size,
                              hipStream_t stream) {
  const float* img = (const float*)d_in[0];
  const float* cap = (const float*)d_in[1];
  const int* imgL = (const int*)d_in[2];
  const int* capL = (const int*)d_in[3];

  char* wsb = (char*)d_ws;
  float* n1 = (float*)wsb;                                       // 16 KB
  float* S = (float*)(wsb + 16384);                              // 16 KB
  _Float16* img_h = (_Float16*)(wsb + 32768);                    // 4 MB
  _Float16* cap_h = (_Float16*)(wsb + 32768 + 4194304);          // 3 MB
  _Float16* G_h = (_Float16*)(wsb + 32768 + 4194304 + 3145728);  // 384 KB

  k_pre<<<320, 512, 0, stream>>>(img, cap, img_h, cap_h, G_h, n1);
  k_fused<<<256, 512, 0, stream>>>(img_h, cap_h, imgL, capL, n1, G_h, S);
  k_loss<<<1, 128, 0, stream>>>(S, (float*)d_out);
}

// Round 16
// 47.422 us; speedup vs baseline: 2.5183x; 2.5183x over previous
//
#include <hip/hip_runtime.h>
#include <math.h>

#define N 64
#define F 64
#define W 40
#define D 512
#define LSM 9.0f
#define LLSE 6.0f
#define MARG 0.2f
#define ESTR 56  // Es row stride in halves

typedef _Float16 f16x8 __attribute__((ext_vector_type(8)));
typedef _Float16 f16x4 __attribute__((ext_vector_type(4)));
typedef float f32x4 __attribute__((ext_vector_type(4)));

__device__ inline void gll16(const void* g, void* l) {
  __builtin_amdgcn_global_load_lds(
      (const __attribute__((address_space(1))) unsigned int*)g,
      (__attribute__((address_space(3))) unsigned int*)l, 16, 0, 0);
}

// layouts (halves), K-chunked (8 chunks of 64) + XOR swizzle baked in:
//  img_h per i: [ch8][f64][64],  halfidx ^ ((f&7)<<3)               (32768)
//  cap_h per j: [ch8][w48][64], halfidx ^ ((w&7)<<3), rows 40..47=0 (24576)
//  G_h  per j: [w48][64] linear, zero outside 40 rows/48 cols       (3072)

// ---------------- k_pre: grid 320 x 512 (proven) ----------------
__global__ __launch_bounds__(512) void k_pre(
    const float* __restrict__ img, const float* __restrict__ cap,
    _Float16* __restrict__ img_h, _Float16* __restrict__ cap_h,
    _Float16* __restrict__ G_h, float* __restrict__ n1) {
  __shared__ __align__(16) _Float16 capT[4 * 48 * 128];  // 48 KB (cap blocks only)
  int t = threadIdx.x;
  int b = blockIdx.x;
  if (b < 256) {
    int i = b >> 2;
    int f = ((b & 3) << 4) + (t >> 5);
    int q = t & 31;  // 16 halves per thread
    const float* row = img + ((size_t)i * F + f) * D + q * 16;
    _Float16* dsti = img_h + (size_t)i * 32768;
    int fsw = (f & 7) << 3;
    float s = 0.f;
    int d0 = q * 16;
    int ch = d0 >> 6, din = d0 & 63;
#pragma unroll
    for (int k = 0; k < 2; ++k) {
      float4 u = *(const float4*)(row + k * 8);
      float4 v = *(const float4*)(row + k * 8 + 4);
      s += u.x * u.x + u.y * u.y + u.z * u.z + u.w * u.w;
      s += v.x * v.x + v.y * v.y + v.z * v.z + v.w * v.w;
      f16x8 h;
      h[0] = (_Float16)u.x; h[1] = (_Float16)u.y; h[2] = (_Float16)u.z; h[3] = (_Float16)u.w;
      h[4] = (_Float16)v.x; h[5] = (_Float16)v.y; h[6] = (_Float16)v.z; h[7] = (_Float16)v.w;
      *(f16x8*)(dsti + ch * 4096 + f * 64 + ((din + k * 8) ^ fsw)) = h;
    }
    s += __shfl_xor(s, 1);
    s += __shfl_xor(s, 2);
    s += __shfl_xor(s, 4);
    s += __shfl_xor(s, 8);
    s += __shfl_xor(s, 16);
    if (q == 0) n1[i * F + f] = sqrtf(s);
  } else {
    int j = b - 256;
    int lane = t & 63, wv = t >> 6;
    const float* src = cap + (size_t)j * W * D;
    _Float16* dst = cap_h + (size_t)j * 24576;
#pragma unroll
    for (int k = 0; k < 6; ++k) {
      int slot = t + k * 512;  // 48 rows x 64 col-chunks
      int w = slot >> 6, d = (slot & 63) * 8;
      float4 u = {0.f, 0.f, 0.f, 0.f}, v = {0.f, 0.f, 0.f, 0.f};
      if (w < W) {
        u = *(const float4*)(src + (size_t)w * D + d);
        v = *(const float4*)(src + (size_t)w * D + d + 4);
      }
      f16x8 h;
      h[0] = (_Float16)u.x; h[1] = (_Float16)u.y; h[2] = (_Float16)u.z; h[3] = (_Float16)u.w;
      h[4] = (_Float16)v.x; h[5] = (_Float16)v.y; h[6] = (_Float16)v.z; h[7] = (_Float16)v.w;
      int wsw = (w & 7) << 3;
      int ch2 = d >> 6, din2 = d & 63;
      *(f16x8*)(dst + ch2 * 3072 + w * 64 + (din2 ^ wsw)) = h;
      int chO = d >> 7, dinO = d & 127;
      *(f16x8*)(capT + chO * 6144 + w * 128 + (dinO ^ wsw)) = h;
    }
    __syncthreads();
    int lane2 = t & 63;
    int rlo = lane2 & 15, hi = lane2 >> 4;
    int koff = hi * 8, sw = (rlo & 7) << 3;
    _Float16* gb = G_h + (size_t)j * 3072;
    for (int tile = wv; tile < 9; tile += 8) {
      int mt = tile / 3, kt = tile % 3;
      f32x4 acc = (f32x4)0.f;
#pragma unroll
      for (int ks = 0; ks < 16; ++ks) {
        int kk = ks * 32 + koff;
        int ch = kk >> 7, din = (kk & 127) ^ sw;
        f16x8 af = *(const f16x8*)(capT + ch * 6144 + (mt * 16 + rlo) * 128 + din);
        f16x8 bf = *(const f16x8*)(capT + ch * 6144 + (kt * 16 + rlo) * 128 + din);
        acc = __builtin_amdgcn_mfma_f32_16x16x32_f16(af, bf, acc, 0, 0, 0);
      }
#pragma unroll
      for (int r = 0; r < 4; ++r) {
        int w = mt * 16 + hi * 4 + r, k = kt * 16 + rlo;
        float val = (w < W && k < W) ? acc[r] : 0.f;
        gb[w * 64 + k] = (_Float16)val;
      }
    }
    // zero G cols 48..63 (K-tail of P2 reads E pad -> A=G cols must be 0)
    if (t < 96) {
      int w = t >> 1, c8 = 48 + (t & 1) * 8;
      *(f16x8*)(gb + w * 64 + c8) = (f16x8)(_Float16)0.f;
    }
  }
}

// ---------------- k_fused: 256 blocks x 512 thr = 1 block/CU ----------------
// GEMM: capMat(3072x512) x imgMat^T -> 192x256 C-tile/block, BK=64, dbuf 2x56KB.
// Wave (wm,wn of 2x4): 96x64 output = TWO complete (j,i) pairs in registers.
// Epilogue v2: P2 = G x E^T puts f on lanes; tail reads E from REGISTERS.
__global__ __launch_bounds__(512, 2) void k_fused(
    const _Float16* __restrict__ img_h, const _Float16* __restrict__ cap_h,
    const int* __restrict__ imgL, const int* __restrict__ capL,
    const float* __restrict__ n1g, const _Float16* __restrict__ G_h,
    float* __restrict__ S) {
  __shared__ __align__(16) char buf[114688];  // 2 x 56KB K-tile dbuf; Es aliased later

  int t = threadIdx.x;
  int lane = t & 63, wv = t >> 6;
  int rlo = lane & 15, hi = lane >> 4;
  int koff = hi * 8;
  int sw = (rlo & 7) << 3;
  int wm = wv >> 2, wn = wv & 3;  // 2 x 4 wave grid

  int bid = blockIdx.x;
  int xcd = bid & 7, s0 = bid >> 3;
  int bj = (xcd & 3) * 4 + (s0 & 3);   // M-tile in [0,16)
  int bi = (xcd >> 2) * 8 + (s0 >> 2); // N-tile in [0,16)

  int i = bi * 4 + wn;       // this wave's image
  int ja = bj * 4 + wm * 2;  // pair a caption; pair b = ja+1
  int iL = imgL[i];
  int cLa = capL[ja], cLb = capL[ja + 1];

  const char* capb = (const char*)cap_h + (size_t)bj * 4 * 49152;
  const char* imgb = (const char*)img_h + (size_t)bi * 4 * 65536;

  // 7 staging descriptors/wave: 56 x 1KB segs per K-tile (A 24KB | B 32KB)
  const char* bsrc[7];
  int cstr[7], mdst[7];
#pragma unroll
  for (int s = 0; s < 7; ++s) {
    int m = s * 8 + wv;
    if (m < 24) {
      bsrc[s] = capb + (m / 6) * 49152 + (m % 6) * 1024 + lane * 16;
      cstr[s] = 6144;
    } else {
      int e = m - 24;
      bsrc[s] = imgb + (e >> 3) * 65536 + (e & 7) * 1024 + lane * 16;
      cstr[s] = 8192;
    }
    mdst[s] = m * 1024;
  }

  f32x4 acc[6][4];
#pragma unroll
  for (int mt = 0; mt < 6; ++mt)
#pragma unroll
    for (int nt = 0; nt < 4; ++nt) acc[mt][nt] = (f32x4)0.f;

  // prologue: stage K-tile 0 (7 gll in flight)
#pragma unroll
  for (int s = 0; s < 7; ++s) gll16(bsrc[s], buf + mdst[s]);

  // ---- K-loop: counted-vmcnt two-barrier pipeline, 8 K-tiles ----
#pragma unroll
  for (int c = 0; c < 8; ++c) {
    if (c < 7) {
      char* db = buf + ((c + 1) & 1) * 57344;
#pragma unroll
      for (int s = 0; s < 7; ++s) gll16(bsrc[s] + (c + 1) * cstr[s], db + mdst[s]);
      asm volatile("s_waitcnt vmcnt(7)" ::: "memory");  // tile-c landed; c+1 in flight
    } else {
      asm volatile("s_waitcnt vmcnt(0)" ::: "memory");
    }
    __builtin_amdgcn_s_barrier();
    __builtin_amdgcn_sched_barrier(0);
    const char* cb = buf + (c & 1) * 57344;
    const _Float16* Al = (const _Float16*)cb;                        // 4 x [48][64]
    const _Float16* Bl = (const _Float16*)(cb + 24576) + wn * 4096;  // my i: [64][64]
#pragma unroll
    for (int ks = 0; ks < 2; ++ks) {
      int col = (ks * 32 + koff) ^ sw;
      f16x8 bf[4], af[6];
#pragma unroll
      for (int nt = 0; nt < 4; ++nt) bf[nt] = *(const f16x8*)(Bl + (nt * 16 + rlo) * 64 + col);
#pragma unroll
      for (int mt = 0; mt < 6; ++mt) {
        int blk = wm * 2 + (mt >= 3 ? 1 : 0);
        int w = (mt >= 3 ? mt - 3 : mt) * 16 + rlo;
        af[mt] = *(const f16x8*)(Al + blk * 3072 + w * 64 + col);
      }
      __builtin_amdgcn_s_setprio(1);
#pragma unroll
      for (int mt = 0; mt < 6; ++mt)
#pragma unroll
        for (int nt = 0; nt < 4; ++nt)
          acc[mt][nt] = __builtin_amdgcn_mfma_f32_16x16x32_f16(af[mt], bf[nt], acc[mt][nt], 0, 0, 0);
      __builtin_amdgcn_s_setprio(0);
    }
    __builtin_amdgcn_sched_barrier(0);
    __builtin_amdgcn_s_barrier();  // reads of buf[c&1] done -> c+2 may overwrite
  }

  // ---- epilogue v2: wave-private, zero barriers, per pair ----
  _Float16* Ew = (_Float16*)(buf + wv * 7168);  // [64][ESTR=56] halves
  float n1lane = n1g[i * F + lane];

#pragma unroll
  for (int p = 0; p < 2; ++p) {
    int j = ja + p;
    int cL = p ? cLb : cLa;
    int mb = p * 3;

    // rnorm: rinv per w from sum_f leaky(A)^2 (f-masked)
    float rinv[3][4];
#pragma unroll
    for (int mt = 0; mt < 3; ++mt)
#pragma unroll
      for (int r = 0; r < 4; ++r) {
        float s = 0.f;
#pragma unroll
        for (int nt = 0; nt < 4; ++nt) {
          float a = acc[mb + mt][nt][r];
          float l = a > 0.f ? a : 0.1f * a;
          s += ((nt * 16 + rlo) < iL) ? l * l : 0.f;
        }
#pragma unroll
        for (int d = 1; d < 16; d <<= 1) s += __shfl_xor(s, d);
        rinv[mt][r] = 1.f / (sqrtf(s) + 1e-8f);
      }

    // fused softmax (logits in [-9,9] -> no max pass) + sn + E to regs + Es write
    float sn[4] = {0.f, 0.f, 0.f, 0.f};
    f16x4 evs[3][4];  // lane-owned E[f = nt*16+rlo][w = mt*16+hi*4+r]
#pragma unroll
    for (int mt = 0; mt < 3; ++mt)
#pragma unroll
      for (int nt = 0; nt < 4; ++nt) {
        f16x4 ev;
#pragma unroll
        for (int r = 0; r < 4; ++r) {
          int w = mt * 16 + hi * 4 + r;
          float a = acc[mb + mt][nt][r];
          float l = a > 0.f ? a : 0.1f * a;
          float e = (w < cL) ? __expf(LSM * l * rinv[mt][r]) : 0.f;
          sn[nt] = fmaf(e, a, sn[nt]);
          ev[r] = (_Float16)e;
        }
        evs[mt][nt] = ev;
        *(f16x4*)(Ew + (nt * 16 + rlo) * ESTR + mt * 16 + hi * 4) = ev;
      }
#pragma unroll
    for (int nt = 0; nt < 4; ++nt) {
      sn[nt] += __shfl_xor(sn[nt], 16);
      sn[nt] += __shfl_xor(sn[nt], 32);
    }

    // P2 = G x E^T (24 MFMA): C[w][f] -> f on lanes (col = rlo)
    const _Float16* gB = G_h + (size_t)j * 3072;
    f32x4 P2[3][4];
#pragma unroll
    for (int wb = 0; wb < 3; ++wb)
#pragma unroll
      for (int fb = 0; fb < 4; ++fb) P2[wb][fb] = (f32x4)0.f;
#pragma unroll
    for (int ks2 = 0; ks2 < 2; ++ks2) {
      int kk2 = ks2 * 32 + koff;
      f16x8 ga[3], eb[4];
#pragma unroll
      for (int wb = 0; wb < 3; ++wb)
        ga[wb] = *(const f16x8*)(gB + (wb * 16 + rlo) * 64 + kk2);
#pragma unroll
      for (int fb = 0; fb < 4; ++fb)
        eb[fb] = *(const f16x8*)(Ew + (fb * 16 + rlo) * ESTR + kk2);
#pragma unroll
      for (int wb = 0; wb < 3; ++wb)
#pragma unroll
        for (int fb = 0; fb < 4; ++fb)
          P2[wb][fb] = __builtin_amdgcn_mfma_f32_16x16x32_f16(ga[wb], eb[fb], P2[wb][fb], 0, 0, 0);
    }

    // tail: n2^2[f] = sum_w P2[w][f]*E[f][w] -- E from REGISTERS (same lane),
    // 2 shfl per f-block; sim+exp once per (lane, fb); ef uniform across hi.
    float ef = 0.f;
#pragma unroll
    for (int fb = 0; fb < 4; ++fb) {
      int f = fb * 16 + rlo;
      float n2s = 0.f;
#pragma unroll
      for (int wb = 0; wb < 3; ++wb)
#pragma unroll
        for (int r = 0; r < 4; ++r)
          n2s = fmaf(P2[wb][fb][r], (float)evs[wb][fb][r], n2s);
      n2s += __shfl_xor(n2s, 16);
      n2s += __shfl_xor(n2s, 32);
      float nm = sn[fb];
      float n1v = __shfl(n1lane, f);
      float denom = n1v * sqrtf(fmaxf(n2s, 0.f));
      float sim = nm / fmaxf(denom, 1e-20f);
      ef += (f < iL) ? __expf(LLSE * sim) : 0.f;
    }
    ef += __shfl_xor(ef, 1);
    ef += __shfl_xor(ef, 2);
    ef += __shfl_xor(ef, 4);
    ef += __shfl_xor(ef, 8);
    if (lane == 0) S[(j << 6) + i] = __logf(ef) * (1.f / LLSE);
  }
}

// ---------------- k_loss ----------------
__global__ void k_loss(const float* __restrict__ S, float* __restrict__ out) {
  __shared__ float red[128];
  int t = threadIdx.x;
  float m = -1e30f;
  if (t < 64) {
    int a = t;
    float da = S[a * N + a];
    for (int b = 0; b < N; ++b)
      if (b != a) m = fmaxf(m, MARG + S[a * N + b] - da);
  } else {
    int b = t - 64;
    float db = S[b * N + b];
    for (int a = 0; a < N; ++a)
      if (a != b) m = fmaxf(m, MARG + S[a * N + b] - db);
  }
  red[t] = fmaxf(m, 0.f);
  __syncthreads();
  if (t < 64) {
    float v = red[t] + red[t + 64];
#pragma unroll
    for (int off = 1; off < 64; off <<= 1) v += __shfl_xor(v, off);
    if (t == 0) *out = v;
  }
}

extern "C" void kernel_launch(void* const* d_in, const int* in_sizes, int n_in,
                              void* d_out, int out_size, void* d_ws, size_t ws_size,
                              hipStream_t stream) {
  const float* img = (const float*)d_in[0];
  const float* cap = (const float*)d_in[1];
  const int* imgL = (const int*)d_in[2];
  const int* capL = (const int*)d_in[3];

  char* wsb = (char*)d_ws;
  float* n1 = (float*)wsb;                                       // 16 KB
  float* S = (float*)(wsb + 16384);                              // 16 KB
  _Float16* img_h = (_Float16*)(wsb + 32768);                    // 4 MB
  _Float16* cap_h = (_Float16*)(wsb + 32768 + 4194304);          // 3 MB
  _Float16* G_h = (_Float16*)(wsb + 32768 + 4194304 + 3145728);  // 384 KB

  k_pre<<<320, 512, 0, stream>>>(img, cap, img_h, cap_h, G_h, n1);
  k_fused<<<256, 512, 0, stream>>>(img_h, cap_h, imgL, capL, n1, G_h, S);
  k_loss<<<1, 128, 0, stream>>>(S, (float*)d_out);
}